// Round 3
// baseline (322.640 us; speedup 1.0000x reference)
//
#include <hip/hip_runtime.h>

#define D_NODE 128
#define D_EDGE 64
#define D_IN 192
#define D_OUT 128

// fp32 -> bf16 (RNE)
static __device__ __forceinline__ unsigned f2bf(float f) {
    unsigned u = __float_as_uint(f);
    return (u + 0x7fffu + ((u >> 16) & 1u)) >> 16;
}

// 8B nontemporal load as two floats (nontemporal builtin rejects HIP float2)
static __device__ __forceinline__ void nt_load_f2(const float* p, float& a, float& b) {
    long long raw = __builtin_nontemporal_load((const long long*)p);
    a = __uint_as_float((unsigned)(raw & 0xffffffffLL));
    b = __uint_as_float((unsigned)((unsigned long long)raw >> 32));
}

// ---------------- CSR build (R5-proven) ----------------

// Histogram rank + x bf16 pack in one pass.
__global__ void k_rank(const int* __restrict__ dst, int* __restrict__ cnt,
                       int* __restrict__ rank, const float2* __restrict__ x2,
                       unsigned* __restrict__ xb, int nx2, int E) {
    int e = blockIdx.x * 256 + threadIdx.x;
    if (e < E) rank[e] = atomicAdd(&cnt[dst[e]], 1);
    if (e < nx2) {
        float2 v = x2[e];
        xb[e] = f2bf(v.x) | (f2bf(v.y) << 16);
    }
}

// Single-block scan (N <= 16384).
__global__ __launch_bounds__(1024) void k_scan(const int* __restrict__ cnt,
                                               int* __restrict__ offsets, int N) {
    __shared__ int wsum[16];
    int tid = threadIdx.x;
    int lane = tid & 63, wid = tid >> 6;
    const int CH = (N + 1023) / 1024;
    int i0 = tid * CH;
    int local[16];
    int lsum = 0;
    for (int c = 0; c < CH; ++c) {
        int i = i0 + c;
        int v = (i < N) ? cnt[i] : 0;
        local[c] = v;
        lsum += v;
    }
    int incl = lsum;
    for (int off = 1; off < 64; off <<= 1) {
        int t = __shfl_up(incl, off, 64);
        if (lane >= off) incl += t;
    }
    if (lane == 63) wsum[wid] = incl;
    __syncthreads();
    if (wid == 0) {
        int s = (lane < 16) ? wsum[lane] : 0;
        for (int off = 1; off < 16; off <<= 1) {
            int t = __shfl_up(s, off, 64);
            if (lane >= off) s += t;
        }
        if (lane < 16) wsum[lane] = s;
    }
    __syncthreads();
    int waveoff = (wid > 0) ? wsum[wid - 1] : 0;
    int run = waveoff + incl - lsum;
    for (int c = 0; c < CH; ++c) {
        int i = i0 + c;
        if (i < N) { offsets[i] = run; run += local[c]; }
    }
    if (tid == 0) offsets[N] = wsum[15];
}

// Atomic-free placement, x4 vectorized.
__global__ void k_place(const int* __restrict__ ei, const int* __restrict__ offsets,
                        const int* __restrict__ rank, int2* __restrict__ csr, int E) {
    int i = blockIdx.x * 256 + threadIdx.x;
    int e = i * 4;
    if (e + 4 <= E) {
        int4 s4 = *(const int4*)(ei + e);
        int4 d4 = *(const int4*)(ei + E + e);
        int4 r4 = *(const int4*)(rank + e);
        csr[offsets[d4.x] + r4.x] = make_int2(s4.x, e + 0);
        csr[offsets[d4.y] + r4.y] = make_int2(s4.y, e + 1);
        csr[offsets[d4.z] + r4.z] = make_int2(s4.z, e + 2);
        csr[offsets[d4.w] + r4.w] = make_int2(s4.w, e + 3);
    } else {
        for (; e < E; ++e)
            csr[offsets[ei[E + e]] + rank[e]] = make_int2(ei[e], e);
    }
}

// ---------------- fused gather + gemm ----------------
// One block per 8-node chunk, 256 threads (4 waves), 2 nodes per wave.
// Paired-lane gather: lanes 0-31 service even edges, lanes 32-63 odd edges,
// each lane loading 8B (uint2 xb / 2xfloat ef) -> one VMEM instruction covers
// TWO edges' 256B rows. Halves VMEM instruction count / vmcnt slots vs R1.
// Accumulators are feature-sliced per half-wave (lane hl owns x-feats
// 4hl..4hl+3 and ef-feats 2hl,2hl+1); one shfl_xor(32) merges halves.
__global__ __launch_bounds__(256) void k_gg(
        const unsigned* __restrict__ xb, const float* __restrict__ ef,
        const int* __restrict__ offsets, const int2* __restrict__ csr,
        const float* __restrict__ W, const float* __restrict__ b,
        float* __restrict__ out, int N) {
    __shared__ float sAgg[8][D_IN];
    __shared__ int scnt[8];
    const int tid  = threadIdx.x;
    const int lane = tid & 63;
    const int hl   = lane & 31;          // position within half-wave
    const int half = lane >> 5;          // 0: even edges, 1: odd edges
    const int wid  = tid >> 6;           // 0..3
    const int n0   = blockIdx.x * 8;

    for (int m = wid; m < 8; m += 4) {
        int node = n0 + m;
        // bank b / bank d alternate for ILP; feature ownership:
        //   x-feats 4hl..4hl+3, ef-feats 2hl..2hl+1
        float bx0 = 0.f, bx1 = 0.f, bx2 = 0.f, bx3 = 0.f, bz0 = 0.f, bz1 = 0.f;
        float dx0 = 0.f, dx1 = 0.f, dx2 = 0.f, dx3 = 0.f, dz0 = 0.f, dz1 = 0.f;
        int start = 0, end = 0;
        if (node < N) {
            start = offsets[node];
            end = offsets[node + 1];
            int j = start;
            for (; j + 8 <= end; j += 8) {
                int2 e8[8];
#pragma unroll
                for (int u = 0; u < 8; ++u) e8[u] = csr[j + u];   // wave-uniform
                uint2 xv[4];
                float eva[4], evb[4];
#pragma unroll
                for (int u = 0; u < 4; ++u) {
                    int s  = half ? e8[2 * u + 1].x : e8[2 * u].x;
                    int id = half ? e8[2 * u + 1].y : e8[2 * u].y;
                    xv[u] = ((const uint2*)(xb + (unsigned)s * 64u))[hl];
                    nt_load_f2(ef + (unsigned)id * 64u + 2u * hl, eva[u], evb[u]);
                }
#pragma unroll
                for (int u = 0; u < 4; ++u) {
                    float fx0 = __uint_as_float(xv[u].x << 16);
                    float fx1 = __uint_as_float(xv[u].x & 0xffff0000u);
                    float fx2 = __uint_as_float(xv[u].y << 16);
                    float fx3 = __uint_as_float(xv[u].y & 0xffff0000u);
                    if (u & 1) {
                        dx0 += fx0; dx1 += fx1; dx2 += fx2; dx3 += fx3;
                        dz0 += eva[u]; dz1 += evb[u];
                    } else {
                        bx0 += fx0; bx1 += fx1; bx2 += fx2; bx3 += fx3;
                        bz0 += eva[u]; bz1 += evb[u];
                    }
                }
            }
            for (; j < end; ++j) {                    // tail: half 0 loads, half 1 idle
                int2 e1 = csr[j];
                if (half == 0) {
                    uint2 xv = ((const uint2*)(xb + (unsigned)e1.x * 64u))[hl];
                    float ea, eb;
                    nt_load_f2(ef + (unsigned)e1.y * 64u + 2u * hl, ea, eb);
                    bx0 += __uint_as_float(xv.x << 16);
                    bx1 += __uint_as_float(xv.x & 0xffff0000u);
                    bx2 += __uint_as_float(xv.y << 16);
                    bx3 += __uint_as_float(xv.y & 0xffff0000u);
                    bz0 += ea;
                    bz1 += eb;
                }
            }
        }
        float sx0 = bx0 + dx0, sx1 = bx1 + dx1, sx2 = bx2 + dx2, sx3 = bx3 + dx3;
        float sz0 = bz0 + dz0, sz1 = bz1 + dz1;
        sx0 += __shfl_xor(sx0, 32);      // merge even/odd edge halves
        sx1 += __shfl_xor(sx1, 32);
        sx2 += __shfl_xor(sx2, 32);
        sx3 += __shfl_xor(sx3, 32);
        sz0 += __shfl_xor(sz0, 32);
        sz1 += __shfl_xor(sz1, 32);
        if (half == 0) {
            *(float4*)&sAgg[m][4 * hl] = make_float4(sx0, sx1, sx2, sx3);
        } else {
            *(float2*)&sAgg[m][128 + 2 * hl] = make_float2(sz0, sz1);
        }
        if (lane == 0) scnt[m] = end - start;
    }
    __syncthreads();

    // ---- gemm: 256 threads; o = tid&127, g = tid>>7 handles nodes g*4..g*4+3 ----
    int o = tid & 127;
    int g = tid >> 7;                    // 0..1
    float acc[4];
#pragma unroll
    for (int m = 0; m < 4; ++m) acc[m] = 0.0f;
    for (int k = 0; k < D_IN; k += 4) {
        float w0 = W[(k + 0) * D_OUT + o];
        float w1 = W[(k + 1) * D_OUT + o];
        float w2 = W[(k + 2) * D_OUT + o];
        float w3 = W[(k + 3) * D_OUT + o];
#pragma unroll
        for (int m = 0; m < 4; ++m) {
            const float4 av = *(const float4*)(&sAgg[g * 4 + m][k]);
            acc[m] += av.x * w0 + av.y * w1 + av.z * w2 + av.w * w3;
        }
    }
    float bo = b[o];
#pragma unroll
    for (int m = 0; m < 4; ++m) {
        int n = n0 + g * 4 + m;
        if (n < N) {
            int c = scnt[g * 4 + m];
            float v = (c > 0) ? (acc[m] / (float)c + bo) : 0.0f;
            __builtin_nontemporal_store(v, &out[(size_t)n * D_OUT + o]);
        }
    }
}

extern "C" void kernel_launch(void* const* d_in, const int* in_sizes, int n_in,
                              void* d_out, int out_size, void* d_ws, size_t ws_size,
                              hipStream_t stream) {
    const float* x  = (const float*)d_in[0];
    const int*   ei = (const int*)d_in[1];   // [2, E] flat: src [0,E), dst [E,2E)
    const float* ef = (const float*)d_in[2];
    const float* W  = (const float*)d_in[3];
    const float* b  = (const float*)d_in[4];
    float* out = (float*)d_out;

    const int N = in_sizes[0] / D_NODE;
    const int E = in_sizes[2] / D_EDGE;
    const int nx2 = in_sizes[0] / 2;

    auto align64 = [](size_t v) { return (v + 63) & ~(size_t)63; };
    char* ws = (char*)d_ws;
    size_t o_cnt = 0;
    size_t o_off = align64(o_cnt + (size_t)N * 4);
    size_t o_rnk = align64(o_off + (size_t)(N + 1) * 4);
    size_t o_csr = align64(o_rnk + (size_t)E * 4);
    size_t o_xb  = align64(o_csr + (size_t)E * 8);
    int*  cnt     = (int*)(ws + o_cnt);
    int*  offsets = (int*)(ws + o_off);
    int*  rank    = (int*)(ws + o_rnk);
    int2* csr     = (int2*)(ws + o_csr);
    unsigned* xb  = (unsigned*)(ws + o_xb);

    int gridR = ((E > nx2 ? E : nx2) + 255) / 256;
    hipMemsetAsync(cnt, 0, (size_t)N * 4, stream);
    k_rank<<<gridR, 256, 0, stream>>>(ei + E, cnt, rank, (const float2*)x, xb, nx2, E);
    k_scan<<<1, 1024, 0, stream>>>(cnt, offsets, N);
    k_place<<<(E / 4 + 255) / 256, 256, 0, stream>>>(ei, offsets, rank, csr, E);
    k_gg<<<(N + 7) / 8, 256, 0, stream>>>(xb, ef, offsets, csr, W, b, out, N);
}